// Round 12
// baseline (257.938 us; speedup 1.0000x reference)
//
#include <hip/hip_runtime.h>
#include <cstdint>

typedef unsigned int u32;
typedef unsigned short u16;

#define N_NODES 100000
#define N_EDGES 3200000
#define F_IN 128
#define DIM 10
#define QB 16            // bf16 elems per padded q row -> 32B
#define HPAD 12          // f32 h2 row stride (48B) for the pool kernel
#define B_GRAPHS 1000
#define RNG 32           // dst nodes per fine bucket
#define NBKT 3136        // 98 coarse * 32 fine
#define CAP 1280         // slots/fine bucket: mean 1024 + 8 sigma
#define NCOARSE 98       // ceil(100000/1024) coarse buckets (dst>>10)
#define CAPC 34816       // slots/coarse bucket: mean 32768 + ~11 sigma
#define CHUNK_C 8192     // edges per k_coarse block (long segments; occupancy
                         // comes from 1024-thread blocks, not more blocks)
#define NBLK_C 391       // ceil(E/CHUNK_C)
#define CHUNK_S 4096     // records per k_split slice
#define SLICES 9         // ceil(CAPC/CHUNK_S)
#define GSTRIDE 16       // cursor padding: one 64B line per cursor

__device__ __forceinline__ u16 f2b(float f) {           // f32 -> bf16 (RNE)
  union { float f; u32 i; } c; c.f = f;
  u32 r = c.i + 0x7FFFu + ((c.i >> 16) & 1u);
  return (u16)(r >> 16);
}
__device__ __forceinline__ float bl(u32 u) {            // low bf16 -> f32
  union { u32 i; float f; } c; c.i = u << 16; return c.f;
}
__device__ __forceinline__ float bh(u32 u) {            // high bf16 -> f32
  union { u32 i; float f; } c; c.i = u & 0xFFFF0000u; return c.f;
}

// 2 threads per node, K split interleaved (k4 = l + 2*it): lane pairs read
// adjacent float4s (x read exactly once, coalesced), 2x waves vs 1 thr/node.
// One shfl_xor stage reduces both p and q; lane 0 stores p, lane 1 stores q.
__global__ __launch_bounds__(256) void k_gemm1(
    const float* __restrict__ x, const float* __restrict__ W,
    float* __restrict__ p1, u16* __restrict__ q1b)
{
  int t = blockIdx.x * 256 + threadIdx.x;
  int i = t >> 1;
  if (i >= N_NODES) return;
  int l = t & 1;
  const float4* __restrict__ xr = (const float4*)(x + (size_t)i * F_IN) + l;
  float ap[DIM], aq[DIM];
  #pragma unroll
  for (int j = 0; j < DIM; ++j) { ap[j] = 0.f; aq[j] = 0.f; }
  #pragma unroll 4
  for (int it = 0; it < 16; ++it) {
    float4 v = xr[it * 2];                    // k4 = l + 2*it
    const float* __restrict__ w0 = W + ((l + 2 * it) * 4) * DIM;
    const float* __restrict__ w1 = w0 + F_IN * DIM;
    #pragma unroll
    for (int j = 0; j < DIM; ++j) {
      ap[j] += v.x * w0[j] + v.y * w0[DIM + j] + v.z * w0[2 * DIM + j] + v.w * w0[3 * DIM + j];
      aq[j] += v.x * w1[j] + v.y * w1[DIM + j] + v.z * w1[2 * DIM + j] + v.w * w1[3 * DIM + j];
    }
  }
  #pragma unroll
  for (int j = 0; j < DIM; ++j) {
    ap[j] += __shfl_xor(ap[j], 1, 2);
    aq[j] += __shfl_xor(aq[j], 1, 2);
  }
  if (l == 0) {
    float* pr = p1 + (size_t)i * DIM;
    #pragma unroll
    for (int j = 0; j < DIM; ++j) pr[j] = ap[j];
  } else {
    u32* qr = (u32*)(q1b + (size_t)i * QB);
    uint4 v0; u32 v1;
    v0.x = (u32)f2b(aq[0]) | ((u32)f2b(aq[1]) << 16);
    v0.y = (u32)f2b(aq[2]) | ((u32)f2b(aq[3]) << 16);
    v0.z = (u32)f2b(aq[4]) | ((u32)f2b(aq[5]) << 16);
    v0.w = (u32)f2b(aq[6]) | ((u32)f2b(aq[7]) << 16);
    v1   = (u32)f2b(aq[8]) | ((u32)f2b(aq[9]) << 16);
    *(uint4*)qr = v0;
    qr[4] = v1;
  }
}

// Pass 1: bucket edges into 98 coarse ranges (1024 dst each). 1024-thread
// blocks: 16 waves/block at 391 blocks -> ~24 waves/CU without shrinking
// the per-(block,bucket) segments (write amp stays ~1.2x).
// Record: ((dst & 1023) << 17) | src
__global__ __launch_bounds__(1024) void k_coarse(
    const int* __restrict__ src, const int* __restrict__ dst,
    u32* __restrict__ gcurc, u32* __restrict__ coarse)
{
  __shared__ u32 hcnt[NCOARSE];
  __shared__ u32 gbase[NCOARSE];
  int tid = threadIdx.x;
  if (tid < NCOARSE) hcnt[tid] = 0u;
  __syncthreads();
  int base = blockIdx.x * CHUNK_C;
  #pragma unroll
  for (int it = 0; it < CHUNK_C / 1024; ++it) {
    int e = base + it * 1024 + tid;
    if (e < N_EDGES) atomicAdd(&hcnt[(u32)dst[e] >> 10], 1u);
  }
  __syncthreads();
  if (tid < NCOARSE) {
    u32 c = hcnt[tid];
    gbase[tid] = c ? atomicAdd(&gcurc[tid * GSTRIDE], c) : 0u;
    hcnt[tid] = 0u;
  }
  __syncthreads();
  #pragma unroll
  for (int it = 0; it < CHUNK_C / 1024; ++it) {
    int e = base + it * 1024 + tid;
    if (e < N_EDGES) {
      u32 d = (u32)dst[e];
      u32 cb = d >> 10;
      u32 ofs = atomicAdd(&hcnt[cb], 1u);
      u32 p = gbase[cb] + ofs;
      if (p < CAPC)   // statistically impossible; memory-safety only
        coarse[(size_t)cb * CAPC + p] = ((d & 1023u) << 17) | (u32)src[e];
    }
  }
}

// Pass 2: split one 4096-record slice of a coarse bucket into its 32 fine
// buckets (512-thread blocks for wave count). Segments ~128 rec = 512B.
// Fine record = v & 0x3FFFFF (dl5 in bits 17..21).
__global__ __launch_bounds__(512) void k_split(
    const u32* __restrict__ gcurc, const u32* __restrict__ coarse,
    u32* __restrict__ gcur, u32* __restrict__ buckets)
{
  int c = blockIdx.x, sl = blockIdx.y;
  int n = min((int)gcurc[c * GSTRIDE], CAPC);
  int beg = sl * CHUNK_S, end = min(beg + CHUNK_S, n);
  if (beg >= end) return;           // uniform across block
  __shared__ u32 lrec[CHUNK_S];     // 16 KB
  __shared__ u32 hist[RNG];
  __shared__ u32 base32[RNG];
  int tid = threadIdx.x;
  if (tid < RNG) hist[tid] = 0u;
  __syncthreads();
  const u32* __restrict__ rc = coarse + (size_t)c * CAPC;
  int cnt = end - beg;
  for (int r = tid; r < cnt; r += 512) {
    u32 v = rc[beg + r];
    lrec[r] = v;
    atomicAdd(&hist[(v >> 22) & 31u], 1u);
  }
  __syncthreads();
  if (tid < RNG) {
    u32 h = hist[tid];
    int fb = (c << 5) + tid;        // == dst>>5
    base32[tid] = h ? atomicAdd(&gcur[fb * GSTRIDE], h) : 0u;
    hist[tid] = 0u;
  }
  __syncthreads();
  for (int r = tid; r < cnt; r += 512) {
    u32 v = lrec[r];
    u32 f = (v >> 22) & 31u;
    u32 ofs = atomicAdd(&hist[f], 1u);
    u32 p = base32[f] + ofs;
    u32 fb = (c << 5) + f;
    if (p < CAP)                    // memory-safety only
      buckets[(size_t)fb * CAP + p] = v & 0x3FFFFFu;
  }
}

// Shared gather machinery: counting-sort records by dl in LDS, then 8 lanes
// per node reduce the contiguous segment in registers (no f32 atomics).
#define SORT_AND_GATHER(QSRC)                                                 \
  int tid = threadIdx.x;                                                      \
  __shared__ u32 lrec[CAP];                                                   \
  __shared__ u32 srt[CAP];                                                    \
  __shared__ u32 hist[RNG];                                                   \
  __shared__ u32 segst[RNG + 1];                                              \
  __shared__ u32 rank[RNG];                                                   \
  if (tid < RNG) { hist[tid] = 0u; rank[tid] = 0u; }                          \
  __syncthreads();                                                            \
  int b = blockIdx.x;                                                         \
  int n = min((int)gcur[b * GSTRIDE], CAP);                                   \
  const u32* __restrict__ rec = buckets + (size_t)b * CAP;                    \
  for (int r = tid; r < n; r += 256) {                                        \
    u32 v = rec[r];                                                           \
    lrec[r] = v;                                                              \
    atomicAdd(&hist[v >> 17], 1u);                                            \
  }                                                                           \
  __syncthreads();                                                            \
  if (tid < RNG) {                                                            \
    u32 h = hist[tid];                                                        \
    u32 v = h;                                                                \
    for (int off = 1; off < RNG; off <<= 1) {                                 \
      u32 t = __shfl_up(v, off, RNG);                                         \
      if (tid >= off) v += t;                                                 \
    }                                                                         \
    segst[tid] = v - h;                                                       \
    if (tid == RNG - 1) segst[RNG] = v;                                       \
  }                                                                           \
  __syncthreads();                                                            \
  for (int r = tid; r < n; r += 256) {                                        \
    u32 v = lrec[r];                                                          \
    u32 dl = v >> 17;                                                         \
    u32 pos = segst[dl] + atomicAdd(&rank[dl], 1u);                           \
    srt[pos] = v & 0x1FFFFu;                                                  \
  }                                                                           \
  __syncthreads();                                                            \
  int g = tid >> 3;                                                           \
  int l = tid & 7;                                                            \
  int st = (int)segst[g], en = (int)segst[g + 1];                             \
  float s[DIM];                                                               \
  _Pragma("unroll")                                                           \
  for (int j = 0; j < DIM; ++j) s[j] = 0.f;                                   \
  int k = st + l;                                                             \
  for (; k + 8 < en; k += 16) {                                               \
    int s0 = (int)srt[k], s1 = (int)srt[k + 8];                               \
    const u32* __restrict__ q0 = (const u32*)(QSRC + (size_t)s0 * QB);        \
    const u32* __restrict__ q1 = (const u32*)(QSRC + (size_t)s1 * QB);        \
    uint4 A0 = *(const uint4*)q0; u32 B0 = q0[4];                             \
    uint4 A1 = *(const uint4*)q1; u32 B1 = q1[4];                             \
    s[0] += bl(A0.x) + bl(A1.x); s[1] += bh(A0.x) + bh(A1.x);                 \
    s[2] += bl(A0.y) + bl(A1.y); s[3] += bh(A0.y) + bh(A1.y);                 \
    s[4] += bl(A0.z) + bl(A1.z); s[5] += bh(A0.z) + bh(A1.z);                 \
    s[6] += bl(A0.w) + bl(A1.w); s[7] += bh(A0.w) + bh(A1.w);                 \
    s[8] += bl(B0) + bl(B1);     s[9] += bh(B0) + bh(B1);                     \
  }                                                                           \
  if (k < en) {                                                               \
    int s0 = (int)srt[k];                                                     \
    const u32* __restrict__ q0 = (const u32*)(QSRC + (size_t)s0 * QB);        \
    uint4 A0 = *(const uint4*)q0; u32 B0 = q0[4];                             \
    s[0] += bl(A0.x); s[1] += bh(A0.x);                                       \
    s[2] += bl(A0.y); s[3] += bh(A0.y);                                       \
    s[4] += bl(A0.z); s[5] += bh(A0.z);                                       \
    s[6] += bl(A0.w); s[7] += bh(A0.w);                                       \
    s[8] += bl(B0);   s[9] += bh(B0);                                         \
  }                                                                           \
  _Pragma("unroll")                                                           \
  for (int m = 1; m < 8; m <<= 1) {                                           \
    _Pragma("unroll")                                                         \
    for (int j = 0; j < DIM; ++j) s[j] += __shfl_xor(s[j], m, 8);             \
  }

// Layer 1: sorted gather + epilogue h = relu(p1+mean), (p2,q2) = h @ W2.
__global__ __launch_bounds__(256) void k_lay1(
    const u32* __restrict__ gcur, const u32* __restrict__ buckets,
    const float* __restrict__ p1, const u16* __restrict__ q1b,
    const float* __restrict__ W2,
    float* __restrict__ p2, u16* __restrict__ q2b)
{
  __shared__ float w[2 * DIM * DIM];
  for (int t = threadIdx.x; t < 2 * DIM * DIM; t += 256) w[t] = W2[t];
  SORT_AND_GATHER(q1b)
  if (l == 0) {
    int i = b * RNG + g;
    if (i < N_NODES) {
      float inv = 1.0f / fmaxf((float)(en - st), 1.0f);
      const float* __restrict__ pr = p1 + (size_t)i * DIM;
      float h[DIM];
      #pragma unroll
      for (int j = 0; j < DIM; ++j) h[j] = fmaxf(pr[j] + s[j] * inv, 0.0f);
      float aa[DIM], bb[DIM];
      #pragma unroll
      for (int j = 0; j < DIM; ++j) {
        float t0 = 0.f, t1 = 0.f;
        #pragma unroll
        for (int kk = 0; kk < DIM; ++kk) {
          t0 += h[kk] * w[kk * DIM + j];
          t1 += h[kk] * w[(DIM + kk) * DIM + j];
        }
        aa[j] = t0; bb[j] = t1;
      }
      float* po = p2 + (size_t)i * DIM;
      #pragma unroll
      for (int j = 0; j < DIM; ++j) po[j] = aa[j];
      u32* qo = (u32*)(q2b + (size_t)i * QB);
      uint4 v0; u32 v1;
      v0.x = (u32)f2b(bb[0]) | ((u32)f2b(bb[1]) << 16);
      v0.y = (u32)f2b(bb[2]) | ((u32)f2b(bb[3]) << 16);
      v0.z = (u32)f2b(bb[4]) | ((u32)f2b(bb[5]) << 16);
      v0.w = (u32)f2b(bb[6]) | ((u32)f2b(bb[7]) << 16);
      v1   = (u32)f2b(bb[8]) | ((u32)f2b(bb[9]) << 16);
      *(uint4*)qo = v0;
      qo[4] = v1;
    }
  }
}

// Layer 2: sorted gather + epilogue h2 = p2 + mean (f32, stride 12).
__global__ __launch_bounds__(256) void k_lay2(
    const u32* __restrict__ gcur, const u32* __restrict__ buckets,
    const float* __restrict__ p2, const u16* __restrict__ q2b,
    float* __restrict__ h2)
{
  SORT_AND_GATHER(q2b)
  if (l == 0) {
    int i = b * RNG + g;
    if (i < N_NODES) {
      float inv = 1.0f / fmaxf((float)(en - st), 1.0f);
      const float* __restrict__ pr = p2 + (size_t)i * DIM;
      float* ho = h2 + (size_t)i * HPAD;
      #pragma unroll
      for (int j = 0; j < DIM; ++j) ho[j] = pr[j] + s[j] * inv;
    }
  }
}

// one wave per graph: binary-search node range in sorted batch, mean-pool,
// dot with Wfc, sigmoid -> out[b]. Zero atomics.
__global__ __launch_bounds__(64) void k_pool(
    const float* __restrict__ h2, const int* __restrict__ batch,
    const float* __restrict__ Wfc, float* __restrict__ out)
{
  int b = blockIdx.x;
  int lo = 0, hi = N_NODES;
  while (lo < hi) { int m = (lo + hi) >> 1; if (batch[m] < b) lo = m + 1; else hi = m; }
  int start = lo;
  hi = N_NODES;
  while (lo < hi) { int m = (lo + hi) >> 1; if (batch[m] < b + 1) lo = m + 1; else hi = m; }
  int end = lo;
  float sum[DIM];
  #pragma unroll
  for (int j = 0; j < DIM; ++j) sum[j] = 0.f;
  for (int r = start + (int)threadIdx.x; r < end; r += 64) {
    const float4* __restrict__ p = (const float4*)(h2 + (size_t)r * HPAD);
    float4 r0 = p[0], r1 = p[1];
    float2 r2 = *(const float2*)(h2 + (size_t)r * HPAD + 8);
    sum[0] += r0.x; sum[1] += r0.y; sum[2] += r0.z; sum[3] += r0.w;
    sum[4] += r1.x; sum[5] += r1.y; sum[6] += r1.z; sum[7] += r1.w;
    sum[8] += r2.x; sum[9] += r2.y;
  }
  #pragma unroll
  for (int m = 1; m < 64; m <<= 1) {
    #pragma unroll
    for (int j = 0; j < DIM; ++j) sum[j] += __shfl_xor(sum[j], m, 64);
  }
  if (threadIdx.x == 0) {
    float inv = 1.0f / fmaxf((float)(end - start), 1.0f);
    float acc = 0.f;
    #pragma unroll
    for (int j = 0; j < DIM; ++j) acc += sum[j] * inv * Wfc[j];
    out[b] = 1.0f / (1.0f + expf(-acc));
  }
}

extern "C" void kernel_launch(void* const* d_in, const int* in_sizes, int n_in,
                              void* d_out, int out_size, void* d_ws, size_t ws_size,
                              hipStream_t stream)
{
  const float* x     = (const float*)d_in[0];
  const int*   ei    = (const int*)d_in[1];
  const int*   batch = (const int*)d_in[2];
  const float* W1    = (const float*)d_in[3];
  const float* W2    = (const float*)d_in[4];
  const float* Wfc   = (const float*)d_in[5];
  float* out = (float*)d_out;

  const int* src = ei;            // edge_index[0]
  const int* dst = ei + N_EDGES;  // edge_index[1]

  // ---- workspace layout (~37 MB). coarse region is dead after k_split,
  //      so q1b/p1/h2 alias into it (k_gemm1 runs after k_split). ----
  u32* gcurc   = (u32*)d_ws;                          // 98*16, pad 2048 (zeroed)
  u32* gcur    = gcurc + 2048;                        // 3136*16 = 50176 (zeroed)
  u32* buckets = gcur + (size_t)NBKT * GSTRIDE;       // 3136*1280 = 16.06 MB
  u32* coarse  = buckets + (size_t)NBKT * CAP;        // 98*34816 = 13.65 MB
  u16* q1b = (u16*)coarse;                            // N*16 bf16 (3.2MB, aliased)
  float* p1 = (float*)(coarse + 800000);              // N*10 f32 (4MB, aliased)
  float* h2 = (float*)(coarse + 1800000);             // N*12 f32 (4.8MB, aliased)
  u32* after = coarse + (size_t)NCOARSE * CAPC;
  u16* q2b = (u16*)after;                             // N*16 bf16 (3.2MB)
  float* p2 = (float*)(after + 800000);               // N*10 f32 (4MB)

  hipMemsetAsync(d_ws, 0, (2048 + (size_t)NBKT * GSTRIDE) * sizeof(u32), stream);

  k_coarse<<<NBLK_C, 1024, 0, stream>>>(src, dst, gcurc, coarse);
  k_split <<<dim3(NCOARSE, SLICES), 512, 0, stream>>>(gcurc, coarse, gcur, buckets);
  k_gemm1 <<<(2 * N_NODES + 255) / 256, 256, 0, stream>>>(x, W1, p1, q1b);
  k_lay1  <<<NBKT, 256, 0, stream>>>(gcur, buckets, p1, q1b, W2, p2, q2b);
  k_lay2  <<<NBKT, 256, 0, stream>>>(gcur, buckets, p2, q2b, h2);
  k_pool  <<<B_GRAPHS, 64, 0, stream>>>(h2, batch, Wfc, out);
}

// Round 13
// 226.722 us; speedup vs baseline: 1.1377x; 1.1377x over previous
//
#include <hip/hip_runtime.h>
#include <cstdint>

typedef unsigned int u32;
typedef unsigned short u16;

#define N_NODES 100000
#define N_EDGES 3200000
#define F_IN 128
#define DIM 10
#define QB 16            // bf16 elems per padded q row -> 32B
#define HPAD 12          // f32 h2 row stride (48B) for the pool kernel
#define B_GRAPHS 1000
#define NBLK_N 391       // ceil(N/256)
#define RNG 32           // dst nodes per fine bucket
#define NBKT 3136        // 98 coarse * 32 fine
#define CAP 1280         // slots/fine bucket: mean 1024 + 8 sigma
#define NCOARSE 98       // ceil(100000/1024) coarse buckets (dst>>10)
#define CAPC 34816       // slots/coarse bucket: mean 32768 + ~11 sigma
#define CHUNK_C 8192     // edges per coarse block (long segments -> low amp)
#define NBLK_C 391       // ceil(E/CHUNK_C)
#define CHUNK_S 4096     // records per k_split slice
#define SLICES 9         // ceil(CAPC/CHUNK_S)
#define GSTRIDE 16       // cursor padding: one 64B line per cursor

__device__ __forceinline__ u16 f2b(float f) {           // f32 -> bf16 (RNE)
  union { float f; u32 i; } c; c.f = f;
  u32 r = c.i + 0x7FFFu + ((c.i >> 16) & 1u);
  return (u16)(r >> 16);
}
__device__ __forceinline__ float bl(u32 u) {            // low bf16 -> f32
  union { u32 i; float f; } c; c.i = u << 16; return c.f;
}
__device__ __forceinline__ float bh(u32 u) {            // high bf16 -> f32
  union { u32 i; float f; } c; c.i = u & 0xFFFF0000u; return c.f;
}

// ---- gemm1 body: 1 thread/node, wave-uniform W indexing (s_loads) ----
__device__ __forceinline__ void gemm_body(
    int bid, int tid,
    const float* __restrict__ x, const float* __restrict__ W,
    float* __restrict__ p1, u16* __restrict__ q1b)
{
  int i = bid * 256 + tid;
  if (i >= N_NODES) return;
  const float4* __restrict__ xr = (const float4*)(x + (size_t)i * F_IN);
  float ap[DIM], aq[DIM];
  #pragma unroll
  for (int j = 0; j < DIM; ++j) { ap[j] = 0.f; aq[j] = 0.f; }
  #pragma unroll 4
  for (int k4 = 0; k4 < F_IN / 4; ++k4) {
    float4 v = xr[k4];
    const float* __restrict__ w0 = W + (k4 * 4) * DIM;
    const float* __restrict__ w1 = W + (F_IN + k4 * 4) * DIM;
    #pragma unroll
    for (int j = 0; j < DIM; ++j) {
      ap[j] += v.x * w0[j] + v.y * w0[DIM + j] + v.z * w0[2 * DIM + j] + v.w * w0[3 * DIM + j];
      aq[j] += v.x * w1[j] + v.y * w1[DIM + j] + v.z * w1[2 * DIM + j] + v.w * w1[3 * DIM + j];
    }
  }
  float* pr = p1 + (size_t)i * DIM;
  #pragma unroll
  for (int j = 0; j < DIM; ++j) pr[j] = ap[j];
  u32* qr = (u32*)(q1b + (size_t)i * QB);
  uint4 v0; u32 v1;
  v0.x = (u32)f2b(aq[0]) | ((u32)f2b(aq[1]) << 16);
  v0.y = (u32)f2b(aq[2]) | ((u32)f2b(aq[3]) << 16);
  v0.z = (u32)f2b(aq[4]) | ((u32)f2b(aq[5]) << 16);
  v0.w = (u32)f2b(aq[6]) | ((u32)f2b(aq[7]) << 16);
  v1   = (u32)f2b(aq[8]) | ((u32)f2b(aq[9]) << 16);
  *(uint4*)qr = v0;
  qr[4] = v1;
}

// ---- coarse body: bucket edges into 98 ranges (1024 dst each) ----
// Record: ((dst & 1023) << 17) | src
__device__ __forceinline__ void coarse_body(
    int bid, int tid,
    const int* __restrict__ src, const int* __restrict__ dst,
    u32* __restrict__ gcurc, u32* __restrict__ coarse)
{
  __shared__ u32 hcnt[NCOARSE];
  __shared__ u32 gbase[NCOARSE];
  if (tid < NCOARSE) hcnt[tid] = 0u;
  __syncthreads();
  int base = bid * CHUNK_C;
  #pragma unroll
  for (int it = 0; it < CHUNK_C / 256; ++it) {
    int e = base + it * 256 + tid;
    if (e < N_EDGES) atomicAdd(&hcnt[(u32)dst[e] >> 10], 1u);
  }
  __syncthreads();
  if (tid < NCOARSE) {
    u32 c = hcnt[tid];
    gbase[tid] = c ? atomicAdd(&gcurc[tid * GSTRIDE], c) : 0u;
    hcnt[tid] = 0u;
  }
  __syncthreads();
  #pragma unroll
  for (int it = 0; it < CHUNK_C / 256; ++it) {
    int e = base + it * 256 + tid;
    if (e < N_EDGES) {
      u32 d = (u32)dst[e];
      u32 cb = d >> 10;
      u32 ofs = atomicAdd(&hcnt[cb], 1u);
      u32 p = gbase[cb] + ofs;
      if (p < CAPC)   // statistically impossible; memory-safety only
        coarse[(size_t)cb * CAPC + p] = ((d & 1023u) << 17) | (u32)src[e];
    }
  }
}

// Fused front: blocks [0,NBLK_C) run coarse bucketing, [NBLK_C,+NBLK_N) run
// gemm1. Independent data; disjoint pipes (LDS-atomics/scatter vs VALU/L1)
// overlap under co-residency instead of serializing as two launches.
__global__ __launch_bounds__(256) void k_front(
    const int* __restrict__ src, const int* __restrict__ dst,
    u32* __restrict__ gcurc, u32* __restrict__ coarse,
    const float* __restrict__ x, const float* __restrict__ W,
    float* __restrict__ p1, u16* __restrict__ q1b)
{
  if (blockIdx.x < NBLK_C)
    coarse_body(blockIdx.x, threadIdx.x, src, dst, gcurc, coarse);
  else
    gemm_body(blockIdx.x - NBLK_C, threadIdx.x, x, W, p1, q1b);
}

// Fallback separate kernels (serial path when ws too small for un-aliasing)
__global__ __launch_bounds__(256) void k_coarse(
    const int* __restrict__ src, const int* __restrict__ dst,
    u32* __restrict__ gcurc, u32* __restrict__ coarse)
{ coarse_body(blockIdx.x, threadIdx.x, src, dst, gcurc, coarse); }

__global__ __launch_bounds__(256) void k_gemm1(
    const float* __restrict__ x, const float* __restrict__ W,
    float* __restrict__ p1, u16* __restrict__ q1b)
{ gemm_body(blockIdx.x, threadIdx.x, x, W, p1, q1b); }

// Pass 2: split one 4096-record slice of a coarse bucket into its 32 fine
// buckets. Per-(block,fine) segments ~128 records = 512B contiguous.
// Fine record = v & 0x3FFFFF (dl5 in bits 17..21).
__global__ __launch_bounds__(512) void k_split(
    const u32* __restrict__ gcurc, const u32* __restrict__ coarse,
    u32* __restrict__ gcur, u32* __restrict__ buckets)
{
  int c = blockIdx.x, sl = blockIdx.y;
  int n = min((int)gcurc[c * GSTRIDE], CAPC);
  int beg = sl * CHUNK_S, end = min(beg + CHUNK_S, n);
  if (beg >= end) return;           // uniform across block
  __shared__ u32 lrec[CHUNK_S];     // 16 KB
  __shared__ u32 hist[RNG];
  __shared__ u32 base32[RNG];
  int tid = threadIdx.x;
  if (tid < RNG) hist[tid] = 0u;
  __syncthreads();
  const u32* __restrict__ rc = coarse + (size_t)c * CAPC;
  int cnt = end - beg;
  for (int r = tid; r < cnt; r += 512) {
    u32 v = rc[beg + r];
    lrec[r] = v;
    atomicAdd(&hist[(v >> 22) & 31u], 1u);
  }
  __syncthreads();
  if (tid < RNG) {
    u32 h = hist[tid];
    int fb = (c << 5) + tid;        // == dst>>5
    base32[tid] = h ? atomicAdd(&gcur[fb * GSTRIDE], h) : 0u;
    hist[tid] = 0u;
  }
  __syncthreads();
  for (int r = tid; r < cnt; r += 512) {
    u32 v = lrec[r];
    u32 f = (v >> 22) & 31u;
    u32 ofs = atomicAdd(&hist[f], 1u);
    u32 p = base32[f] + ofs;
    u32 fb = (c << 5) + f;
    if (p < CAP)                    // memory-safety only
      buckets[(size_t)fb * CAP + p] = v & 0x3FFFFFu;
  }
}

// Shared gather machinery: counting-sort records by dl in LDS, then 8 lanes
// per node reduce the contiguous segment in registers (no f32 atomics).
#define SORT_AND_GATHER(QSRC)                                                 \
  int tid = threadIdx.x;                                                      \
  __shared__ u32 lrec[CAP];                                                   \
  __shared__ u32 srt[CAP];                                                    \
  __shared__ u32 hist[RNG];                                                   \
  __shared__ u32 segst[RNG + 1];                                              \
  __shared__ u32 rank[RNG];                                                   \
  if (tid < RNG) { hist[tid] = 0u; rank[tid] = 0u; }                          \
  __syncthreads();                                                            \
  int b = blockIdx.x;                                                         \
  int n = min((int)gcur[b * GSTRIDE], CAP);                                   \
  const u32* __restrict__ rec = buckets + (size_t)b * CAP;                    \
  for (int r = tid; r < n; r += 256) {                                        \
    u32 v = rec[r];                                                           \
    lrec[r] = v;                                                              \
    atomicAdd(&hist[v >> 17], 1u);                                            \
  }                                                                           \
  __syncthreads();                                                            \
  if (tid < RNG) {                                                            \
    u32 h = hist[tid];                                                        \
    u32 v = h;                                                                \
    for (int off = 1; off < RNG; off <<= 1) {                                 \
      u32 t = __shfl_up(v, off, RNG);                                         \
      if (tid >= off) v += t;                                                 \
    }                                                                         \
    segst[tid] = v - h;                                                       \
    if (tid == RNG - 1) segst[RNG] = v;                                       \
  }                                                                           \
  __syncthreads();                                                            \
  for (int r = tid; r < n; r += 256) {                                        \
    u32 v = lrec[r];                                                          \
    u32 dl = v >> 17;                                                         \
    u32 pos = segst[dl] + atomicAdd(&rank[dl], 1u);                           \
    srt[pos] = v & 0x1FFFFu;                                                  \
  }                                                                           \
  __syncthreads();                                                            \
  int g = tid >> 3;                                                           \
  int l = tid & 7;                                                            \
  int st = (int)segst[g], en = (int)segst[g + 1];                             \
  float s[DIM];                                                               \
  _Pragma("unroll")                                                           \
  for (int j = 0; j < DIM; ++j) s[j] = 0.f;                                   \
  int k = st + l;                                                             \
  for (; k + 8 < en; k += 16) {                                               \
    int s0 = (int)srt[k], s1 = (int)srt[k + 8];                               \
    const u32* __restrict__ q0 = (const u32*)(QSRC + (size_t)s0 * QB);        \
    const u32* __restrict__ q1 = (const u32*)(QSRC + (size_t)s1 * QB);        \
    uint4 A0 = *(const uint4*)q0; u32 B0 = q0[4];                             \
    uint4 A1 = *(const uint4*)q1; u32 B1 = q1[4];                             \
    s[0] += bl(A0.x) + bl(A1.x); s[1] += bh(A0.x) + bh(A1.x);                 \
    s[2] += bl(A0.y) + bl(A1.y); s[3] += bh(A0.y) + bh(A1.y);                 \
    s[4] += bl(A0.z) + bl(A1.z); s[5] += bh(A0.z) + bh(A1.z);                 \
    s[6] += bl(A0.w) + bl(A1.w); s[7] += bh(A0.w) + bh(A1.w);                 \
    s[8] += bl(B0) + bl(B1);     s[9] += bh(B0) + bh(B1);                     \
  }                                                                           \
  if (k < en) {                                                               \
    int s0 = (int)srt[k];                                                     \
    const u32* __restrict__ q0 = (const u32*)(QSRC + (size_t)s0 * QB);        \
    uint4 A0 = *(const uint4*)q0; u32 B0 = q0[4];                             \
    s[0] += bl(A0.x); s[1] += bh(A0.x);                                       \
    s[2] += bl(A0.y); s[3] += bh(A0.y);                                       \
    s[4] += bl(A0.z); s[5] += bh(A0.z);                                       \
    s[6] += bl(A0.w); s[7] += bh(A0.w);                                       \
    s[8] += bl(B0);   s[9] += bh(B0);                                         \
  }                                                                           \
  _Pragma("unroll")                                                           \
  for (int m = 1; m < 8; m <<= 1) {                                           \
    _Pragma("unroll")                                                         \
    for (int j = 0; j < DIM; ++j) s[j] += __shfl_xor(s[j], m, 8);             \
  }

// Layer 1: sorted gather + epilogue h = relu(p1+mean), (p2,q2) = h @ W2.
__global__ __launch_bounds__(256) void k_lay1(
    const u32* __restrict__ gcur, const u32* __restrict__ buckets,
    const float* __restrict__ p1, const u16* __restrict__ q1b,
    const float* __restrict__ W2,
    float* __restrict__ p2, u16* __restrict__ q2b)
{
  __shared__ float w[2 * DIM * DIM];
  for (int t = threadIdx.x; t < 2 * DIM * DIM; t += 256) w[t] = W2[t];
  SORT_AND_GATHER(q1b)
  if (l == 0) {
    int i = b * RNG + g;
    if (i < N_NODES) {
      float inv = 1.0f / fmaxf((float)(en - st), 1.0f);
      const float* __restrict__ pr = p1 + (size_t)i * DIM;
      float h[DIM];
      #pragma unroll
      for (int j = 0; j < DIM; ++j) h[j] = fmaxf(pr[j] + s[j] * inv, 0.0f);
      float aa[DIM], bb[DIM];
      #pragma unroll
      for (int j = 0; j < DIM; ++j) {
        float t0 = 0.f, t1 = 0.f;
        #pragma unroll
        for (int kk = 0; kk < DIM; ++kk) {
          t0 += h[kk] * w[kk * DIM + j];
          t1 += h[kk] * w[(DIM + kk) * DIM + j];
        }
        aa[j] = t0; bb[j] = t1;
      }
      float* po = p2 + (size_t)i * DIM;
      #pragma unroll
      for (int j = 0; j < DIM; ++j) po[j] = aa[j];
      u32* qo = (u32*)(q2b + (size_t)i * QB);
      uint4 v0; u32 v1;
      v0.x = (u32)f2b(bb[0]) | ((u32)f2b(bb[1]) << 16);
      v0.y = (u32)f2b(bb[2]) | ((u32)f2b(bb[3]) << 16);
      v0.z = (u32)f2b(bb[4]) | ((u32)f2b(bb[5]) << 16);
      v0.w = (u32)f2b(bb[6]) | ((u32)f2b(bb[7]) << 16);
      v1   = (u32)f2b(bb[8]) | ((u32)f2b(bb[9]) << 16);
      *(uint4*)qo = v0;
      qo[4] = v1;
    }
  }
}

// Layer 2: sorted gather + epilogue h2 = p2 + mean (f32, stride 12).
__global__ __launch_bounds__(256) void k_lay2(
    const u32* __restrict__ gcur, const u32* __restrict__ buckets,
    const float* __restrict__ p2, const u16* __restrict__ q2b,
    float* __restrict__ h2)
{
  SORT_AND_GATHER(q2b)
  if (l == 0) {
    int i = b * RNG + g;
    if (i < N_NODES) {
      float inv = 1.0f / fmaxf((float)(en - st), 1.0f);
      const float* __restrict__ pr = p2 + (size_t)i * DIM;
      float* ho = h2 + (size_t)i * HPAD;
      #pragma unroll
      for (int j = 0; j < DIM; ++j) ho[j] = pr[j] + s[j] * inv;
    }
  }
}

// one wave per graph: binary-search node range in sorted batch, mean-pool,
// dot with Wfc, sigmoid -> out[b]. Zero atomics.
__global__ __launch_bounds__(64) void k_pool(
    const float* __restrict__ h2, const int* __restrict__ batch,
    const float* __restrict__ Wfc, float* __restrict__ out)
{
  int b = blockIdx.x;
  int lo = 0, hi = N_NODES;
  while (lo < hi) { int m = (lo + hi) >> 1; if (batch[m] < b) lo = m + 1; else hi = m; }
  int start = lo;
  hi = N_NODES;
  while (lo < hi) { int m = (lo + hi) >> 1; if (batch[m] < b + 1) lo = m + 1; else hi = m; }
  int end = lo;
  float sum[DIM];
  #pragma unroll
  for (int j = 0; j < DIM; ++j) sum[j] = 0.f;
  for (int r = start + (int)threadIdx.x; r < end; r += 64) {
    const float4* __restrict__ p = (const float4*)(h2 + (size_t)r * HPAD);
    float4 r0 = p[0], r1 = p[1];
    float2 r2 = *(const float2*)(h2 + (size_t)r * HPAD + 8);
    sum[0] += r0.x; sum[1] += r0.y; sum[2] += r0.z; sum[3] += r0.w;
    sum[4] += r1.x; sum[5] += r1.y; sum[6] += r1.z; sum[7] += r1.w;
    sum[8] += r2.x; sum[9] += r2.y;
  }
  #pragma unroll
  for (int m = 1; m < 64; m <<= 1) {
    #pragma unroll
    for (int j = 0; j < DIM; ++j) sum[j] += __shfl_xor(sum[j], m, 64);
  }
  if (threadIdx.x == 0) {
    float inv = 1.0f / fmaxf((float)(end - start), 1.0f);
    float acc = 0.f;
    #pragma unroll
    for (int j = 0; j < DIM; ++j) acc += sum[j] * inv * Wfc[j];
    out[b] = 1.0f / (1.0f + expf(-acc));
  }
}

extern "C" void kernel_launch(void* const* d_in, const int* in_sizes, int n_in,
                              void* d_out, int out_size, void* d_ws, size_t ws_size,
                              hipStream_t stream)
{
  const float* x     = (const float*)d_in[0];
  const int*   ei    = (const int*)d_in[1];
  const int*   batch = (const int*)d_in[2];
  const float* W1    = (const float*)d_in[3];
  const float* W2    = (const float*)d_in[4];
  const float* Wfc   = (const float*)d_in[5];
  float* out = (float*)d_out;

  const int* src = ei;            // edge_index[0]
  const int* dst = ei + N_EDGES;  // edge_index[1]

  // ---- workspace layout (u32 element offsets) ----
  u32* wsp = (u32*)d_ws;
  u32* gcurc   = wsp;                                 // 2048 (zeroed)
  u32* gcur    = gcurc + 2048;                        // 3136*16 = 50176 (zeroed)
  u32* buckets = gcur + (size_t)NBKT * GSTRIDE;       // 4,014,080
  u32* coarse  = buckets + (size_t)NBKT * CAP;        // 3,411,968
  u32* after   = coarse + (size_t)NCOARSE * CAPC;
  u16* q2b = (u16*)after;                             // 800,000 u32
  float* p2 = (float*)(after + 800000);               // 1,000,000 u32
  float* h2 = (float*)coarse;                         // aliases coarse (dead by lay2)

  // Un-aliased q1b/p1 (fused path) need ws >= 11,078,272 u32 (~44.3 MB).
  const size_t NEED = (size_t)(2048 + 50176) + (size_t)NBKT * CAP
                    + (size_t)NCOARSE * CAPC + 800000 + 1000000   // base ~37 MB
                    + 800000 + 1000000;                            // + q1b, p1
  bool fused = ws_size >= NEED * sizeof(u32);

  u16* q1b;
  float* p1;
  if (fused) {
    q1b = (u16*)(after + 1800000);                    // fresh region
    p1  = (float*)(after + 2600000);
  } else {
    q1b = (u16*)coarse;                               // alias (serial path)
    p1  = (float*)(coarse + 800000);
  }

  hipMemsetAsync(d_ws, 0, (2048 + (size_t)NBKT * GSTRIDE) * sizeof(u32), stream);

  if (fused) {
    // coarse-bucketing and gemm1 are independent -> one launch, overlap.
    k_front<<<NBLK_C + NBLK_N, 256, 0, stream>>>(src, dst, gcurc, coarse,
                                                 x, W1, p1, q1b);
    k_split<<<dim3(NCOARSE, SLICES), 512, 0, stream>>>(gcurc, coarse, gcur, buckets);
  } else {
    k_coarse<<<NBLK_C, 256, 0, stream>>>(src, dst, gcurc, coarse);
    k_split <<<dim3(NCOARSE, SLICES), 512, 0, stream>>>(gcurc, coarse, gcur, buckets);
    k_gemm1 <<<NBLK_N, 256, 0, stream>>>(x, W1, p1, q1b);  // after split (alias)
  }
  k_lay1<<<NBKT, 256, 0, stream>>>(gcur, buckets, p1, q1b, W2, p2, q2b);
  k_lay2<<<NBKT, 256, 0, stream>>>(gcur, buckets, p2, q2b, h2);
  k_pool<<<B_GRAPHS, 64, 0, stream>>>(h2, batch, Wfc, out);
}